// Round 5
// baseline (294.046 us; speedup 1.0000x reference)
//
#include <hip/hip_runtime.h>
#include <hip/hip_bf16.h>

// SphereConv N=2, CIN=64, COUT=64, H=256, W=512, K2=9.
// Round 4: barrier-free K-loop. Each wave owns 16 pixels x all 64 COUT.
// Lane (quad q, col) gathers 4x16B corners for pixel=col, channels q*8..+8,
// interpolates in registers -> the MFMA B-fragment directly. No S-tile LDS,
// no in-loop __syncthreads (round 3 showed barriers drain vmcnt(0) and kill
// prefetch). A-frags (4 COUT groups) re-loaded per step from L2-resident wTr.

constexpr int N_ = 2;
constexpr int CIN = 64;
constexpr int COUT = 64;
constexpr int H_ = 256;
constexpr int W_ = 512;
constexpr int K2 = 9;
constexpr int HW = H_ * W_;
constexpr int NSTEP = (CIN * K2) / 32;  // 18

typedef __attribute__((ext_vector_type(8))) short short8;
typedef __attribute__((ext_vector_type(4))) float floatx4;
typedef __attribute__((ext_vector_type(2))) float floatx2;

__device__ __forceinline__ float bfhi2f(unsigned u) {  // bits already in hi half
  return __uint_as_float(u);
}

// wTr[(g*18 + s)*64*8 + lane*8 + j] = bf16(weight[o = 16g + (lane&15)]
//                                          [kk = 32s + (lane>>4)*8 + j])
// kk -> tap = kk>>6, c = kk&63; weight flat (o*CIN + c)*9 + tap.
__global__ void prep_w(const float* __restrict__ w, ushort* __restrict__ wTr) {
  int i = blockIdx.x * blockDim.x + threadIdx.x;
  if (i >= 4 * NSTEP * 64 * 8) return;
  int j = i & 7;
  int lane = (i >> 3) & 63;
  int s = (i >> 9) % NSTEP;
  int g = i / (512 * NSTEP);
  int o = g * 16 + (lane & 15);
  int kk = s * 32 + (lane >> 4) * 8 + j;
  int tap = kk >> 6, c = kk & 63;
  __hip_bfloat16 b = __float2bfloat16(w[(o * CIN + c) * K2 + tap]);
  wTr[i] = *(ushort*)&b;
}

// x[n][c][hw] fp32 -> xt[n][hw][c] bf16. Register-only: thread owns 8px x 8ch.
__global__ __launch_bounds__(256) void transpose_x(
    const float* __restrict__ x, ushort* __restrict__ xt) {
  int b = blockIdx.x;            // N * (HW/256) = 1024 blocks, 256 px each
  int n = b >> 9;
  int hw0 = (b & 511) * 256;
  int t = threadIdx.x;
  int c0 = (t & 7) * 8;
  int p0 = (t >> 3) * 8;
  const float* xn = x + (size_t)n * CIN * HW + hw0 + p0;
  ushort* xo = xt + (size_t)n * HW * CIN + (size_t)(hw0 + p0) * 64 + c0;
  float4 v[8][2];
#pragma unroll
  for (int ci = 0; ci < 8; ++ci) {
    const float* r = xn + (size_t)(c0 + ci) * HW;
    v[ci][0] = *(const float4*)r;
    v[ci][1] = *(const float4*)(r + 4);
  }
#pragma unroll
  for (int pi = 0; pi < 8; ++pi) {
    __align__(16) unsigned d4[4];
#pragma unroll
    for (int d = 0; d < 4; ++d) {
      float fa = (&v[2 * d][pi >> 2].x)[pi & 3];
      float fb = (&v[2 * d + 1][pi >> 2].x)[pi & 3];
      __hip_bfloat16 lo = __float2bfloat16(fa);
      __hip_bfloat16 hi = __float2bfloat16(fb);
      d4[d] = ((unsigned)*(ushort*)&hi << 16) | *(ushort*)&lo;
    }
    *(uint4*)(xo + (size_t)pi * 64) = *(const uint4*)d4;
  }
}

__global__ __launch_bounds__(256, 4) void sphere_conv_mfma(
    const ushort* __restrict__ xt, const ushort* __restrict__ wTr,
    const float* __restrict__ pos, float* __restrict__ out) {
  __shared__ int off_lds[K2 * 64];      // 2.3 KB: packed o00|dx<<20|dy<<21
  __shared__ uint2 wgt_lds[K2 * 64];    // 4.6 KB: 4 corner wgts, bf16-packed

  int tid = threadIdx.x;
  int blk = blockIdx.x;
  int n = blk >> 11;                    // HW/64 = 2048 tiles per batch
  int ptile = (blk & 2047) * 64;

  // ---- phase 0: bilinear offsets/weights for 9 taps x 64 pixels ----
  for (int i = tid; i < K2 * 64; i += 256) {
    int t = i >> 6, p = i & 63;
    int hw = ptile + p;
    float py = pos[(2 * t + 0) * HW + hw];
    float px = pos[(2 * t + 1) * HW + hw];
    float y0f = floorf(py), x0f = floorf(px);
    float dy = py - y0f, dx = px - x0f;
    float y1f = y0f + 1.f, x1f = x0f + 1.f;
    float vy0 = (y0f >= 0.f && y0f <= (float)(H_ - 1)) ? 1.f : 0.f;
    float vy1 = (y1f >= 0.f && y1f <= (float)(H_ - 1)) ? 1.f : 0.f;
    float vx0 = (x0f >= 0.f && x0f <= (float)(W_ - 1)) ? 1.f : 0.f;
    float vx1 = (x1f >= 0.f && x1f <= (float)(W_ - 1)) ? 1.f : 0.f;
    float w00 = (1.f - dy) * (1.f - dx) * vy0 * vx0;
    float w01 = (1.f - dy) * dx * vy0 * vx1;
    float w10 = dy * (1.f - dx) * vy1 * vx0;
    float w11 = dy * dx * vy1 * vx1;
    int y0c = (int)fminf(fmaxf(y0f, 0.f), (float)(H_ - 1));
    int y1c = (int)fminf(fmaxf(y1f, 0.f), (float)(H_ - 1));
    int x0c = (int)fminf(fmaxf(x0f, 0.f), (float)(W_ - 1));
    int x1c = (int)fminf(fmaxf(x1f, 0.f), (float)(W_ - 1));
    int o00 = y0c * W_ + x0c;
    off_lds[i] = o00 | ((x1c - x0c) << 20) | ((y1c - y0c) << 21);
    __hip_bfloat16 b00 = __float2bfloat16(w00), b01 = __float2bfloat16(w01);
    __hip_bfloat16 b10 = __float2bfloat16(w10), b11 = __float2bfloat16(w11);
    unsigned lo = ((unsigned)*(ushort*)&b01 << 16) | *(ushort*)&b00;
    unsigned hi = ((unsigned)*(ushort*)&b11 << 16) | *(ushort*)&b10;
    wgt_lds[i] = make_uint2(lo, hi);
  }
  __syncthreads();  // the ONLY barrier

  int lane = tid & 63, wv = tid >> 6;
  int col = lane & 15, quad = lane >> 4;
  const ushort* xtn = xt + (size_t)n * HW * CIN;

  floatx4 acc[4];
#pragma unroll
  for (int g = 0; g < 4; ++g) acc[g] = (floatx4)0.f;

#pragma unroll
  for (int s = 0; s < NSTEP; ++s) {
    int t = s >> 1;
    int c0 = ((s & 1) << 5) + (quad << 3);  // lane's 8-channel slice
    int pk = off_lds[t * 64 + wv * 16 + col];
    uint2 wr = wgt_lds[t * 64 + wv * 16 + col];
    float w00 = bfhi2f(wr.x << 16);
    float w01 = bfhi2f(wr.x & 0xFFFF0000u);
    float w10 = bfhi2f(wr.y << 16);
    float w11 = bfhi2f(wr.y & 0xFFFF0000u);
    int o00 = pk & 0x1FFFF;
    int dx1 = (pk >> 20) & 1;
    int dyW = ((pk >> 21) & 1) * W_;
    const ushort* b0 = xtn + (size_t)o00 * 64 + c0;
    short8 v00 = *(const short8*)b0;
    short8 v01 = *(const short8*)(b0 + dx1 * 64);
    short8 v10 = *(const short8*)(b0 + dyW * 64);
    short8 v11 = *(const short8*)(b0 + (dyW + dx1) * 64);

    // interp: b_frag[j] = sum_c w_c * corner_c[j], j = 0..7 (k = quad*8+j)
    const unsigned* u0 = (const unsigned*)&v00;
    const unsigned* u1 = (const unsigned*)&v01;
    const unsigned* u2 = (const unsigned*)&v10;
    const unsigned* u3 = (const unsigned*)&v11;
    __align__(16) unsigned bfr[4];
#pragma unroll
    for (int d = 0; d < 4; ++d) {
      floatx2 f0 = {bfhi2f(u0[d] << 16), bfhi2f(u0[d] & 0xFFFF0000u)};
      floatx2 f1 = {bfhi2f(u1[d] << 16), bfhi2f(u1[d] & 0xFFFF0000u)};
      floatx2 f2 = {bfhi2f(u2[d] << 16), bfhi2f(u2[d] & 0xFFFF0000u)};
      floatx2 f3 = {bfhi2f(u3[d] << 16), bfhi2f(u3[d] & 0xFFFF0000u)};
      floatx2 r = floatx2{w00, w00} * f0;
      r = __builtin_elementwise_fma(floatx2{w01, w01}, f1, r);
      r = __builtin_elementwise_fma(floatx2{w10, w10}, f2, r);
      r = __builtin_elementwise_fma(floatx2{w11, w11}, f3, r);
      __hip_bfloat16 lo = __float2bfloat16(r.x);
      __hip_bfloat16 hi = __float2bfloat16(r.y);
      bfr[d] = ((unsigned)*(ushort*)&hi << 16) | *(ushort*)&lo;
    }
    short8 bfrag = *(const short8*)bfr;

#pragma unroll
    for (int g = 0; g < 4; ++g) {
      short8 afrag = *(const short8*)(wTr + ((size_t)(g * NSTEP + s) * 64 + lane) * 8);
      acc[g] = __builtin_amdgcn_mfma_f32_16x16x32_bf16(afrag, bfrag, acc[g], 0, 0, 0);
    }
  }

  // ---- epilogue: acc[g] row = quad*4+r -> o = g*16+quad*4+r, col = pixel ----
#pragma unroll
  for (int g = 0; g < 4; ++g) {
#pragma unroll
    for (int r = 0; r < 4; ++r) {
      int o = g * 16 + quad * 4 + r;
      out[(size_t)(n * COUT + o) * HW + ptile + wv * 16 + col] = acc[g][r];
    }
  }
}

extern "C" void kernel_launch(void* const* d_in, const int* in_sizes, int n_in,
                              void* d_out, int out_size, void* d_ws, size_t ws_size,
                              hipStream_t stream) {
  const float* x   = (const float*)d_in[0];  // (2, 64, 256, 512) fp32
  const float* w   = (const float*)d_in[1];  // (64, 64, 3, 3) fp32
  const float* pos = (const float*)d_in[2];  // (18, 256, 512) fp32
  float* out = (float*)d_out;                // (2, 64, 256, 512) fp32

  // ws layout: wTr bf16 [72 KB] at 0; xt bf16 [67.1 MB] at 128 KB.
  ushort* wTr = (ushort*)d_ws;
  ushort* xt = (ushort*)((char*)d_ws + (128 << 10));

  prep_w<<<(4 * NSTEP * 64 * 8 + 255) / 256, 256, 0, stream>>>(w, wTr);
  transpose_x<<<N_ * (HW / 256), 256, 0, stream>>>(x, xt);

  int nblk = N_ * (HW / 64);  // 4096 blocks, 64 px each
  sphere_conv_mfma<<<nblk, 256, 0, stream>>>(xt, wTr, pos, out);
}